// Round 1
// baseline (2252.210 us; speedup 1.0000x reference)
//
#include <hip/hip_runtime.h>

// ---------------------------------------------------------------------------
// 6-layer GCN: per layer  h = x @ W ;  agg = D^-1/2 (A+I) D^-1/2 h + b ; lrelu
// Buffers in d_ws: deg(int N) | dinv(f32 N) | bufA(f32 N*64) | bufB(f32 N*64)
// ---------------------------------------------------------------------------

__device__ __forceinline__ float readlane_f(float v, int l) {
    union { float f; int i; } u;
    u.f = v;
    u.i = __builtin_amdgcn_readlane(u.i, l);
    return u.f;
}

__global__ __launch_bounds__(256) void count_deg(const int* __restrict__ dst,
                                                 int* __restrict__ deg, int E) {
    int i = blockIdx.x * blockDim.x + threadIdx.x;
    int stride = gridDim.x * blockDim.x;
    for (; i < E; i += stride) atomicAdd(&deg[dst[i]], 1);
}

__global__ __launch_bounds__(256) void compute_dinv(const int* __restrict__ deg,
                                                    float* __restrict__ dinv, int n) {
    int i = blockIdx.x * blockDim.x + threadIdx.x;
    int stride = gridDim.x * blockDim.x;
    for (; i < n; i += stride) {
        float d = (float)(deg[i] + 1);   // +1 self loop; always >= 1
        dinv[i] = 1.0f / sqrtf(d);
    }
}

// h[row,l] = sum_k lrelu?(x[row,k]) * W[k,l]
// agg[row,l] = b[l] + dinv[row]^2 * h[row,l]   (self-loop + bias init)
// NOTE: x and agg may alias (in-place layer update). Each row is owned by
// exactly one wave and x[row] is fully read before agg[row] is written, so
// this is safe; x/agg intentionally NOT __restrict__.
template <int K, bool LRELU>
__global__ __launch_bounds__(256) void gemm_agg_init(
    const float* x, const float* __restrict__ W, const float* __restrict__ b,
    const float* __restrict__ dinv, float* __restrict__ h, float* agg, int n) {
    const int lane = threadIdx.x & 63;
    const int gw = blockIdx.x * (blockDim.x >> 6) + (threadIdx.x >> 6);
    const int nw = gridDim.x * (blockDim.x >> 6);

    // W column `lane` in registers
    float wreg[K];
#pragma unroll
    for (int k = 0; k < K; ++k) wreg[k] = W[k * 64 + lane];
    const float bl = b[lane];

    for (int row = gw; row < n; row += nw) {
        float xv0 = x[(size_t)row * K + lane];
        if (LRELU) xv0 = xv0 >= 0.f ? xv0 : 0.2f * xv0;
        float xv1 = 0.f;
        if (K == 128) {
            xv1 = x[(size_t)row * K + 64 + lane];
            if (LRELU) xv1 = xv1 >= 0.f ? xv1 : 0.2f * xv1;
        }
        // 4 partial accumulators to break the fma dependency chain
        float a0 = 0.f, a1 = 0.f, a2 = 0.f, a3 = 0.f;
#pragma unroll
        for (int k = 0; k < 64; k += 4) {
            a0 = fmaf(readlane_f(xv0, k + 0), wreg[k + 0], a0);
            a1 = fmaf(readlane_f(xv0, k + 1), wreg[k + 1], a1);
            a2 = fmaf(readlane_f(xv0, k + 2), wreg[k + 2], a2);
            a3 = fmaf(readlane_f(xv0, k + 3), wreg[k + 3], a3);
        }
        if (K == 128) {
#pragma unroll
            for (int k = 0; k < 64; k += 4) {
                a0 = fmaf(readlane_f(xv1, k + 0), wreg[64 + k + 0], a0);
                a1 = fmaf(readlane_f(xv1, k + 1), wreg[64 + k + 1], a1);
                a2 = fmaf(readlane_f(xv1, k + 2), wreg[64 + k + 2], a2);
                a3 = fmaf(readlane_f(xv1, k + 3), wreg[64 + k + 3], a3);
            }
        }
        float acc = (a0 + a1) + (a2 + a3);
        h[(size_t)row * 64 + lane] = acc;
        float di = dinv[row];
        agg[(size_t)row * 64 + lane] = fmaf(di * di, acc, bl);
    }
}

// agg[dst,l] += dinv[src]*dinv[dst] * h[src,l]   one wave per edge, lane=feature
__global__ __launch_bounds__(256) void edge_agg64(
    const float* __restrict__ h, const int* __restrict__ src,
    const int* __restrict__ dst, const float* __restrict__ dinv,
    float* __restrict__ agg, int E) {
    const int lane = threadIdx.x & 63;
    int w = blockIdx.x * (blockDim.x >> 6) + (threadIdx.x >> 6);
    const int nw = gridDim.x * (blockDim.x >> 6);
    for (int e = w; e < E; e += nw) {
        int s = src[e];
        int d = dst[e];
        float nrm = dinv[s] * dinv[d];
        float v = h[(size_t)s * 64 + lane] * nrm;
        atomicAdd(&agg[(size_t)d * 64 + lane], v);
    }
}

// Final layer: K=64 -> 4 outputs. LRELU always applied to input.
__global__ __launch_bounds__(256) void gemm4_agg_init(
    const float* __restrict__ x, const float* __restrict__ W,  // [64,4]
    const float* __restrict__ b, const float* __restrict__ dinv,
    float* __restrict__ h4, float* __restrict__ out, int n) {
    int i = blockIdx.x * blockDim.x + threadIdx.x;
    int stride = gridDim.x * blockDim.x;
    for (; i < n; i += stride) {
        const float4* xr = (const float4*)(x + (size_t)i * 64);
        float a0 = 0.f, a1 = 0.f, a2 = 0.f, a3 = 0.f;
#pragma unroll
        for (int k4 = 0; k4 < 16; ++k4) {
            float4 xv = xr[k4];
            float e0 = xv.x >= 0.f ? xv.x : 0.2f * xv.x;
            float e1 = xv.y >= 0.f ? xv.y : 0.2f * xv.y;
            float e2 = xv.z >= 0.f ? xv.z : 0.2f * xv.z;
            float e3 = xv.w >= 0.f ? xv.w : 0.2f * xv.w;
            int k = k4 * 4;
            a0 = fmaf(e0, W[(k + 0) * 4 + 0], a0);
            a1 = fmaf(e0, W[(k + 0) * 4 + 1], a1);
            a2 = fmaf(e0, W[(k + 0) * 4 + 2], a2);
            a3 = fmaf(e0, W[(k + 0) * 4 + 3], a3);
            a0 = fmaf(e1, W[(k + 1) * 4 + 0], a0);
            a1 = fmaf(e1, W[(k + 1) * 4 + 1], a1);
            a2 = fmaf(e1, W[(k + 1) * 4 + 2], a2);
            a3 = fmaf(e1, W[(k + 1) * 4 + 3], a3);
            a0 = fmaf(e2, W[(k + 2) * 4 + 0], a0);
            a1 = fmaf(e2, W[(k + 2) * 4 + 1], a1);
            a2 = fmaf(e2, W[(k + 2) * 4 + 2], a2);
            a3 = fmaf(e2, W[(k + 2) * 4 + 3], a3);
            a0 = fmaf(e3, W[(k + 3) * 4 + 0], a0);
            a1 = fmaf(e3, W[(k + 3) * 4 + 1], a1);
            a2 = fmaf(e3, W[(k + 3) * 4 + 2], a2);
            a3 = fmaf(e3, W[(k + 3) * 4 + 3], a3);
        }
        float4 hv = make_float4(a0, a1, a2, a3);
        ((float4*)h4)[i] = hv;
        float di = dinv[i];
        float d2 = di * di;
        float4 ov = make_float4(fmaf(d2, a0, b[0]), fmaf(d2, a1, b[1]),
                                fmaf(d2, a2, b[2]), fmaf(d2, a3, b[3]));
        ((float4*)out)[i] = ov;
    }
}

__global__ __launch_bounds__(256) void edge_agg4(
    const float* __restrict__ h4, const int* __restrict__ src,
    const int* __restrict__ dst, const float* __restrict__ dinv,
    float* __restrict__ out, int E) {
    int t = blockIdx.x * blockDim.x + threadIdx.x;
    int stride = gridDim.x * blockDim.x;
    for (int e = t; e < E; e += stride) {
        int s = src[e];
        int d = dst[e];
        float nrm = dinv[s] * dinv[d];
        float4 v = ((const float4*)h4)[s];
        atomicAdd(&out[(size_t)d * 4 + 0], v.x * nrm);
        atomicAdd(&out[(size_t)d * 4 + 1], v.y * nrm);
        atomicAdd(&out[(size_t)d * 4 + 2], v.z * nrm);
        atomicAdd(&out[(size_t)d * 4 + 3], v.w * nrm);
    }
}

extern "C" void kernel_launch(void* const* d_in, const int* in_sizes, int n_in,
                              void* d_out, int out_size, void* d_ws, size_t ws_size,
                              hipStream_t stream) {
    const float* x  = (const float*)d_in[0];
    const int* ei   = (const int*)d_in[1];
    const float* W0 = (const float*)d_in[2];
    const float* b0 = (const float*)d_in[3];
    const float* W1 = (const float*)d_in[4];
    const float* b1 = (const float*)d_in[5];
    const float* W2 = (const float*)d_in[6];
    const float* b2 = (const float*)d_in[7];
    const float* W3 = (const float*)d_in[8];
    const float* b3 = (const float*)d_in[9];
    const float* W4 = (const float*)d_in[10];
    const float* b4 = (const float*)d_in[11];
    const float* W5 = (const float*)d_in[12];
    const float* b5 = (const float*)d_in[13];

    const int N = in_sizes[0] / 128;
    const int E = in_sizes[1] / 2;
    const int* src = ei;       // edge_index[0] = message sources
    const int* dstp = ei + E;  // edge_index[1] = aggregation targets

    float* ws = (float*)d_ws;
    int* deg    = (int*)ws;                  // N ints
    float* dinv = ws + N;                    // N floats
    float* bufA = ws + 2 * (size_t)N;        // N*64 floats (h)
    float* bufB = bufA + 64 * (size_t)N;     // N*64 floats (agg / next x)

    hipMemsetAsync(deg, 0, (size_t)N * sizeof(int), stream);
    count_deg<<<2048, 256, 0, stream>>>(dstp, deg, E);
    compute_dinv<<<(N + 255) / 256, 256, 0, stream>>>(deg, dinv, N);

    // Layer 0: x[N,128] -> bufA(h), bufB(agg init); then edge atomics
    gemm_agg_init<128, false><<<2048, 256, 0, stream>>>(x, W0, b0, dinv, bufA, bufB, N);
    edge_agg64<<<2048, 256, 0, stream>>>(bufA, src, dstp, dinv, bufB, E);

    // Layers 1-4: in-place bufB -> (h=bufA, agg=bufB)
    const float* Ws[4] = {W1, W2, W3, W4};
    const float* bs[4] = {b1, b2, b3, b4};
    for (int l = 0; l < 4; ++l) {
        gemm_agg_init<64, true><<<2048, 256, 0, stream>>>(bufB, Ws[l], bs[l], dinv, bufA, bufB, N);
        edge_agg64<<<2048, 256, 0, stream>>>(bufA, src, dstp, dinv, bufB, E);
    }

    // Layer 5: bufB -> h4 in bufA, out init; then edge atomics into d_out
    gemm4_agg_init<<<1024, 256, 0, stream>>>(bufB, W5, b5, dinv, bufA, (float*)d_out, N);
    edge_agg4<<<2048, 256, 0, stream>>>(bufA, src, dstp, dinv, (float*)d_out, E);
}

// Round 2
// 739.355 us; speedup vs baseline: 3.0462x; 3.0462x over previous
//
#include <hip/hip_runtime.h>

// ---------------------------------------------------------------------------
// 6-layer GCN. Per layer: h = lrelu?(x) @ W ; agg = D^-1/2 (A+I) D^-1/2 h + b
// R1: CSR-based aggregation (no atomics in the hot path).
// d_ws layout (4B elements, offsets 64-elem aligned):
//   rowptr[N+1] | dinv[N] | ssrc[E] | bsums[128] | bufA[64N] | bufB[64N]
// cnt/wp alias the bufA region during graph build (done before bufA is used).
// ---------------------------------------------------------------------------

__device__ __forceinline__ float readlane_f(float v, int l) {
    union { float f; int i; } u;
    u.f = v;
    u.i = __builtin_amdgcn_readlane(u.i, l);
    return u.f;
}

__global__ __launch_bounds__(256) void count_deg(const int* __restrict__ dst,
                                                 int* __restrict__ cnt, int E) {
    int i = blockIdx.x * blockDim.x + threadIdx.x;
    int stride = gridDim.x * blockDim.x;
    for (; i < E; i += stride) atomicAdd(&cnt[dst[i]], 1);
}

__global__ __launch_bounds__(256) void compute_dinv(const int* __restrict__ cnt,
                                                    float* __restrict__ dinv, int n) {
    int i = blockIdx.x * blockDim.x + threadIdx.x;
    int stride = gridDim.x * blockDim.x;
    for (; i < n; i += stride) {
        float d = (float)(cnt[i] + 1);   // +1 self loop; always >= 1
        dinv[i] = 1.0f / sqrtf(d);
    }
}

// --- exclusive scan of cnt[N] -> rowptr[N], 1024 elements per block ---------
__global__ __launch_bounds__(256) void scan_block_sums(const int* __restrict__ cnt,
                                                       int* __restrict__ bsums, int n) {
    int tid = threadIdx.x;
    int i0 = blockIdx.x * 1024 + tid * 4;
    int c0 = 0, c1 = 0, c2 = 0, c3 = 0;
    if (i0 + 3 < n) {
        int4 v = *(const int4*)(cnt + i0);
        c0 = v.x; c1 = v.y; c2 = v.z; c3 = v.w;
    } else {
        if (i0     < n) c0 = cnt[i0];
        if (i0 + 1 < n) c1 = cnt[i0 + 1];
        if (i0 + 2 < n) c2 = cnt[i0 + 2];
        if (i0 + 3 < n) c3 = cnt[i0 + 3];
    }
    int t = c0 + c1 + c2 + c3;
#pragma unroll
    for (int off = 1; off < 64; off <<= 1) t += __shfl_xor(t, off);
    __shared__ int wsum[4];
    int wid = tid >> 6, lane = tid & 63;
    if (lane == 0) wsum[wid] = t;
    __syncthreads();
    if (tid == 0) bsums[blockIdx.x] = wsum[0] + wsum[1] + wsum[2] + wsum[3];
}

__global__ void scan_bsums(int* __restrict__ bsums, int* __restrict__ rowptr_last, int nb) {
    if (threadIdx.x == 0 && blockIdx.x == 0) {
        int run = 0;
        for (int i = 0; i < nb; ++i) { int v = bsums[i]; bsums[i] = run; run += v; }
        rowptr_last[0] = run;   // rowptr[N] == E
    }
}

// reads cnt (== cntwp), writes exclusive scan to rowptr AND back to cntwp (wp cursor)
__global__ __launch_bounds__(256) void scan_write(const int* __restrict__ bsums,
                                                  int* __restrict__ cntwp,
                                                  int* __restrict__ rowptr, int n) {
    int tid = threadIdx.x, wid = tid >> 6, lane = tid & 63;
    int i0 = blockIdx.x * 1024 + tid * 4;
    int c0 = 0, c1 = 0, c2 = 0, c3 = 0;
    bool full = (i0 + 3 < n);
    if (full) {
        int4 v = *(const int4*)(cntwp + i0);
        c0 = v.x; c1 = v.y; c2 = v.z; c3 = v.w;
    } else {
        if (i0     < n) c0 = cntwp[i0];
        if (i0 + 1 < n) c1 = cntwp[i0 + 1];
        if (i0 + 2 < n) c2 = cntwp[i0 + 2];
        if (i0 + 3 < n) c3 = cntwp[i0 + 3];
    }
    int t = c0 + c1 + c2 + c3;
    int incl = t;
#pragma unroll
    for (int off = 1; off < 64; off <<= 1) {
        int v = __shfl_up(incl, off);
        if (lane >= off) incl += v;
    }
    __shared__ int wsum[4];
    if (lane == 63) wsum[wid] = incl;
    __syncthreads();
    int wbase = 0;
    for (int w2 = 0; w2 < wid; ++w2) wbase += wsum[w2];
    int base = bsums[blockIdx.x] + wbase + (incl - t);   // exclusive for this thread
    int e0 = base, e1 = base + c0, e2 = e1 + c1, e3 = e2 + c2;
    if (full) {
        *(int4*)(rowptr + i0) = make_int4(e0, e1, e2, e3);
        *(int4*)(cntwp  + i0) = make_int4(e0, e1, e2, e3);
    } else {
        if (i0     < n) { rowptr[i0]     = e0; cntwp[i0]     = e0; }
        if (i0 + 1 < n) { rowptr[i0 + 1] = e1; cntwp[i0 + 1] = e1; }
        if (i0 + 2 < n) { rowptr[i0 + 2] = e2; cntwp[i0 + 2] = e2; }
        if (i0 + 3 < n) { rowptr[i0 + 3] = e3; cntwp[i0 + 3] = e3; }
    }
}

__global__ __launch_bounds__(256) void scatter_edges(const int* __restrict__ src,
                                                     const int* __restrict__ dst,
                                                     int* __restrict__ wp,
                                                     int* __restrict__ ssrc, int E) {
    int i = blockIdx.x * blockDim.x + threadIdx.x;
    int stride = gridDim.x * blockDim.x;
    for (; i < E; i += stride) {
        int d = dst[i];
        int pos = atomicAdd(&wp[d], 1);
        ssrc[pos] = src[i];
    }
}

// --- dense transform: h[row,l] = sum_k lrelu?(x[row,k]) * W[k,l] ------------
template <int K, bool LRELU>
__global__ __launch_bounds__(256) void gemm_h(
    const float* __restrict__ x, const float* __restrict__ W,
    float* __restrict__ h, int n) {
    const int lane = threadIdx.x & 63;
    const int gw = blockIdx.x * (blockDim.x >> 6) + (threadIdx.x >> 6);
    const int nw = gridDim.x * (blockDim.x >> 6);

    float wreg[K];
#pragma unroll
    for (int k = 0; k < K; ++k) wreg[k] = W[k * 64 + lane];

    for (int row = gw; row < n; row += nw) {
        float xv0 = x[(size_t)row * K + lane];
        if (LRELU) xv0 = xv0 >= 0.f ? xv0 : 0.2f * xv0;
        float xv1 = 0.f;
        if (K == 128) {
            xv1 = x[(size_t)row * K + 64 + lane];
            if (LRELU) xv1 = xv1 >= 0.f ? xv1 : 0.2f * xv1;
        }
        float a0 = 0.f, a1 = 0.f, a2 = 0.f, a3 = 0.f;
#pragma unroll
        for (int k = 0; k < 64; k += 4) {
            a0 = fmaf(readlane_f(xv0, k + 0), wreg[k + 0], a0);
            a1 = fmaf(readlane_f(xv0, k + 1), wreg[k + 1], a1);
            a2 = fmaf(readlane_f(xv0, k + 2), wreg[k + 2], a2);
            a3 = fmaf(readlane_f(xv0, k + 3), wreg[k + 3], a3);
        }
        if (K == 128) {
#pragma unroll
            for (int k = 0; k < 64; k += 4) {
                a0 = fmaf(readlane_f(xv1, k + 0), wreg[64 + k + 0], a0);
                a1 = fmaf(readlane_f(xv1, k + 1), wreg[64 + k + 1], a1);
                a2 = fmaf(readlane_f(xv1, k + 2), wreg[64 + k + 2], a2);
                a3 = fmaf(readlane_f(xv1, k + 3), wreg[64 + k + 3], a3);
            }
        }
        h[(size_t)row * 64 + lane] = (a0 + a1) + (a2 + a3);
    }
}

// --- CSR aggregation: one wave per dst node, lane = feature -----------------
__global__ __launch_bounds__(256) void csr_agg64(
    const float* __restrict__ h, const int* __restrict__ rowptr,
    const int* __restrict__ ssrc, const float* __restrict__ dinv,
    const float* __restrict__ b, float* __restrict__ agg, int n) {
    const int lane = threadIdx.x & 63;
    int w = blockIdx.x * (blockDim.x >> 6) + (threadIdx.x >> 6);
    const int nw = gridDim.x * (blockDim.x >> 6);
    const float bl = b[lane];
    for (int d = w; d < n; d += nw) {
        const float di = dinv[d];
        float acc = fmaf(di * di, h[(size_t)d * 64 + lane], bl);
        int e = rowptr[d], end = rowptr[d + 1];
        for (; e + 4 <= end; e += 4) {
            int s0 = ssrc[e], s1 = ssrc[e + 1], s2 = ssrc[e + 2], s3 = ssrc[e + 3];
            float n0 = di * dinv[s0], n1 = di * dinv[s1];
            float n2 = di * dinv[s2], n3 = di * dinv[s3];
            float v0 = h[(size_t)s0 * 64 + lane], v1 = h[(size_t)s1 * 64 + lane];
            float v2 = h[(size_t)s2 * 64 + lane], v3 = h[(size_t)s3 * 64 + lane];
            acc = fmaf(v0, n0, acc);
            acc = fmaf(v1, n1, acc);
            acc = fmaf(v2, n2, acc);
            acc = fmaf(v3, n3, acc);
        }
        for (; e < end; ++e) {
            int s = ssrc[e];
            acc = fmaf(h[(size_t)s * 64 + lane], di * dinv[s], acc);
        }
        agg[(size_t)d * 64 + lane] = acc;
    }
}

// --- final layer: K=64 -> 4, lrelu on input ---------------------------------
__global__ __launch_bounds__(256) void gemm4_h(
    const float* __restrict__ x, const float* __restrict__ W,  // [64,4]
    float* __restrict__ h4, int n) {
    int i = blockIdx.x * blockDim.x + threadIdx.x;
    int stride = gridDim.x * blockDim.x;
    for (; i < n; i += stride) {
        const float4* xr = (const float4*)(x + (size_t)i * 64);
        float a0 = 0.f, a1 = 0.f, a2 = 0.f, a3 = 0.f;
#pragma unroll
        for (int k4 = 0; k4 < 16; ++k4) {
            float4 xv = xr[k4];
            float e0 = xv.x >= 0.f ? xv.x : 0.2f * xv.x;
            float e1 = xv.y >= 0.f ? xv.y : 0.2f * xv.y;
            float e2 = xv.z >= 0.f ? xv.z : 0.2f * xv.z;
            float e3 = xv.w >= 0.f ? xv.w : 0.2f * xv.w;
            int k = k4 * 4;
            a0 = fmaf(e0, W[(k + 0) * 4 + 0], a0); a1 = fmaf(e0, W[(k + 0) * 4 + 1], a1);
            a2 = fmaf(e0, W[(k + 0) * 4 + 2], a2); a3 = fmaf(e0, W[(k + 0) * 4 + 3], a3);
            a0 = fmaf(e1, W[(k + 1) * 4 + 0], a0); a1 = fmaf(e1, W[(k + 1) * 4 + 1], a1);
            a2 = fmaf(e1, W[(k + 1) * 4 + 2], a2); a3 = fmaf(e1, W[(k + 1) * 4 + 3], a3);
            a0 = fmaf(e2, W[(k + 2) * 4 + 0], a0); a1 = fmaf(e2, W[(k + 2) * 4 + 1], a1);
            a2 = fmaf(e2, W[(k + 2) * 4 + 2], a2); a3 = fmaf(e2, W[(k + 2) * 4 + 3], a3);
            a0 = fmaf(e3, W[(k + 3) * 4 + 0], a0); a1 = fmaf(e3, W[(k + 3) * 4 + 1], a1);
            a2 = fmaf(e3, W[(k + 3) * 4 + 2], a2); a3 = fmaf(e3, W[(k + 3) * 4 + 3], a3);
        }
        ((float4*)h4)[i] = make_float4(a0, a1, a2, a3);
    }
}

__global__ __launch_bounds__(256) void csr_agg4(
    const float* __restrict__ h4, const int* __restrict__ rowptr,
    const int* __restrict__ ssrc, const float* __restrict__ dinv,
    const float* __restrict__ b, float* __restrict__ out, int n) {
    int i = blockIdx.x * blockDim.x + threadIdx.x;
    int stride = gridDim.x * blockDim.x;
    float b0 = b[0], b1 = b[1], b2 = b[2], b3 = b[3];
    for (; i < n; i += stride) {
        float di = dinv[i];
        float d2 = di * di;
        float4 hv = ((const float4*)h4)[i];
        float a0 = fmaf(d2, hv.x, b0), a1 = fmaf(d2, hv.y, b1);
        float a2 = fmaf(d2, hv.z, b2), a3 = fmaf(d2, hv.w, b3);
        int e = rowptr[i], end = rowptr[i + 1];
        for (; e < end; ++e) {
            int s = ssrc[e];
            float nrm = di * dinv[s];
            float4 v = ((const float4*)h4)[s];
            a0 = fmaf(nrm, v.x, a0); a1 = fmaf(nrm, v.y, a1);
            a2 = fmaf(nrm, v.z, a2); a3 = fmaf(nrm, v.w, a3);
        }
        ((float4*)out)[i] = make_float4(a0, a1, a2, a3);
    }
}

static inline size_t al64(size_t x) { return (x + 63) & ~(size_t)63; }

extern "C" void kernel_launch(void* const* d_in, const int* in_sizes, int n_in,
                              void* d_out, int out_size, void* d_ws, size_t ws_size,
                              hipStream_t stream) {
    const float* x  = (const float*)d_in[0];
    const int* ei   = (const int*)d_in[1];
    const float* W0 = (const float*)d_in[2];
    const float* b0 = (const float*)d_in[3];
    const float* W1 = (const float*)d_in[4];
    const float* b1 = (const float*)d_in[5];
    const float* W2 = (const float*)d_in[6];
    const float* b2 = (const float*)d_in[7];
    const float* W3 = (const float*)d_in[8];
    const float* b3 = (const float*)d_in[9];
    const float* W4 = (const float*)d_in[10];
    const float* b4 = (const float*)d_in[11];
    const float* W5 = (const float*)d_in[12];
    const float* b5 = (const float*)d_in[13];

    const int N = in_sizes[0] / 128;
    const int E = in_sizes[1] / 2;
    const int* src  = ei;       // edge_index[0] = message sources
    const int* dstp = ei + E;   // edge_index[1] = aggregation targets

    float* ws = (float*)d_ws;
    size_t off = 0;
    int*   rowptr = (int*)(ws + off);   off += al64((size_t)N + 1);
    float* dinv   = ws + off;           off += al64((size_t)N);
    int*   ssrc   = (int*)(ws + off);   off += al64((size_t)E);
    int*   bsums  = (int*)(ws + off);   off += 128;
    float* bufA   = ws + off;           off += (size_t)64 * N;
    float* bufB   = ws + off;
    int*   cnt    = (int*)bufA;         // graph-build temp; freed before bufA's first use

    const int nb = (N + 1023) / 1024;   // scan blocks

    // ---- graph build (once per call) ----
    hipMemsetAsync(cnt, 0, (size_t)N * sizeof(int), stream);
    count_deg<<<2048, 256, 0, stream>>>(dstp, cnt, E);
    compute_dinv<<<(N + 255) / 256, 256, 0, stream>>>(cnt, dinv, N);
    scan_block_sums<<<nb, 256, 0, stream>>>(cnt, bsums, N);
    scan_bsums<<<1, 64, 0, stream>>>(bsums, rowptr + N, nb);
    scan_write<<<nb, 256, 0, stream>>>(bsums, cnt, rowptr, N);   // cnt -> wp
    scatter_edges<<<2048, 256, 0, stream>>>(src, dstp, cnt, ssrc, E);

    // ---- layer 0: x[N,128] ----
    gemm_h<128, false><<<2048, 256, 0, stream>>>(x, W0, bufA, N);
    csr_agg64<<<2048, 256, 0, stream>>>(bufA, rowptr, ssrc, dinv, b0, bufB, N);

    // ---- layers 1-4 ----
    const float* Ws[4] = {W1, W2, W3, W4};
    const float* bs[4] = {b1, b2, b3, b4};
    for (int l = 0; l < 4; ++l) {
        gemm_h<64, true><<<2048, 256, 0, stream>>>(bufB, Ws[l], bufA, N);
        csr_agg64<<<2048, 256, 0, stream>>>(bufA, rowptr, ssrc, dinv, bs[l], bufB, N);
    }

    // ---- layer 5: 64 -> 4 ----
    gemm4_h<<<1024, 256, 0, stream>>>(bufB, W5, bufA, N);
    csr_agg4<<<2048, 256, 0, stream>>>(bufA, rowptr, ssrc, dinv, b5, (float*)d_out, N);
}

// Round 3
// 599.780 us; speedup vs baseline: 3.7551x; 1.2327x over previous
//
#include <hip/hip_runtime.h>

// ---------------------------------------------------------------------------
// 6-layer GCN. Per layer: h = lrelu?(x) @ W ; agg = D^-1/2 (A+I) D^-1/2 h + b
// R2: bucketed CSR build (LDS atomics only in the hot paths).
//   Bucket = 128 consecutive dst ids. NB = ceil(N/128) (<=1024 assumed).
// d_ws layout: rowptr[N+1] | dinv[N] | ssrc[E] | bufA[64N] | bufB[64N]
// Build temps (ghist/base/cursor/bsrc/bdl) alias into bufA (first real use of
// bufA is layer 0's gemm, after the build is complete).
// ---------------------------------------------------------------------------

__device__ __forceinline__ float readlane_f(float v, int l) {
    union { float f; int i; } u;
    u.f = v;
    u.i = __builtin_amdgcn_readlane(u.i, l);
    return u.f;
}

// --- pass 1: coarse histogram of dst>>7 into NB buckets ---------------------
__global__ __launch_bounds__(256) void bucket_hist(const int* __restrict__ dst,
                                                   int* __restrict__ ghist,
                                                   int E, int NB) {
    __shared__ int h[1024];
    for (int i = threadIdx.x; i < NB; i += 256) h[i] = 0;
    __syncthreads();
    int i = blockIdx.x * blockDim.x + threadIdx.x;
    int stride = gridDim.x * blockDim.x;
    for (; i < E; i += stride) atomicAdd(&h[dst[i] >> 7], 1);
    __syncthreads();
    for (int j = threadIdx.x; j < NB; j += 256) {
        int c = h[j];
        if (c) atomicAdd(&ghist[j], c);
    }
}

// --- pass 2: exclusive scan of bucket counts (single block, 1024 thr) -------
__global__ void bucket_scan(const int* __restrict__ ghist, int* __restrict__ base,
                            int* __restrict__ cursor, int NB, int E) {
    int tid = threadIdx.x, lane = tid & 63, wid = tid >> 6;
    int v = (tid < NB) ? ghist[tid] : 0;
    int incl = v;
#pragma unroll
    for (int off = 1; off < 64; off <<= 1) {
        int t = __shfl_up(incl, off);
        if (lane >= off) incl += t;
    }
    __shared__ int ws[16];
    if (lane == 63) ws[wid] = incl;
    __syncthreads();
    if (tid == 0) {
        int run = 0;
        for (int i = 0; i < 16; ++i) { int t = ws[i]; ws[i] = run; run += t; }
    }
    __syncthreads();
    int excl = ws[wid] + incl - v;
    if (tid < NB) { base[tid] = excl; cursor[tid] = excl; }
    if (tid == 0) base[NB] = E;
}

// --- pass 3: scatter edges into bucket-sorted (bsrc, bdl) -------------------
// Per 4096-edge chunk: LDS histogram -> one global reservation per bucket ->
// LDS-cursor scatter. Global atomics: ~NB per block instead of per edge.
__global__ __launch_bounds__(256) void bucket_scatter(
    const int* __restrict__ src, const int* __restrict__ dst,
    int* __restrict__ cursor, int* __restrict__ bsrc,
    unsigned char* __restrict__ bdl, int E, int NB) {
    __shared__ int h[1024];
    __shared__ int rb[1024];
    const int CH = 4096;
    for (int c0 = blockIdx.x * CH; c0 < E; c0 += gridDim.x * CH) {
        int cend = c0 + CH < E ? c0 + CH : E;
        for (int j = threadIdx.x; j < NB; j += 256) h[j] = 0;
        __syncthreads();
        for (int i = c0 + threadIdx.x; i < cend; i += 256)
            atomicAdd(&h[dst[i] >> 7], 1);
        __syncthreads();
        for (int j = threadIdx.x; j < NB; j += 256) {
            int c = h[j];
            rb[j] = c ? atomicAdd(&cursor[j], c) : 0;
            h[j] = 0;
        }
        __syncthreads();
        for (int i = c0 + threadIdx.x; i < cend; i += 256) {
            int d = dst[i];
            int b = d >> 7;
            int p = rb[b] + atomicAdd(&h[b], 1);
            bsrc[p] = src[i];
            bdl[p] = (unsigned char)(d & 127);
        }
        __syncthreads();
    }
}

// --- pass 4: per-bucket CSR finalize: rowptr, dinv, ssrc --------------------
__global__ __launch_bounds__(256) void bucket_finalize(
    const int* __restrict__ base, const int* __restrict__ bsrc,
    const unsigned char* __restrict__ bdl, int* __restrict__ rowptr,
    int* __restrict__ ssrc, float* __restrict__ dinv, int N, int NB, int E) {
    __shared__ int cnt[128];
    __shared__ int cur[128];
    __shared__ int w0sum;
    const int tid = threadIdx.x;
    const int lane = tid & 63;
    for (int b = blockIdx.x; b < NB; b += gridDim.x) {
        const int s = base[b], e = base[b + 1];
        const int d0 = b << 7;
        const int w = (N - d0 < 128) ? (N - d0) : 128;
        if (tid < 128) cnt[tid] = 0;
        __syncthreads();
        for (int i = s + tid; i < e; i += 256) atomicAdd(&cnt[bdl[i]], 1);
        __syncthreads();
        int v = (tid < 128) ? cnt[tid] : 0;
        int incl = v;
#pragma unroll
        for (int off = 1; off < 64; off <<= 1) {
            int t = __shfl_up(incl, off);
            if (lane >= off) incl += t;
        }
        if (tid == 63) w0sum = incl;
        __syncthreads();
        int excl = incl - v + ((tid >= 64 && tid < 128) ? w0sum : 0);
        if (tid < 128) cur[tid] = s + excl;
        if (tid < w) {
            rowptr[d0 + tid] = s + excl;
            dinv[d0 + tid] = rsqrtf((float)(v + 1));   // +1 self loop
        }
        __syncthreads();
        for (int i = s + tid; i < e; i += 256) {
            int p = atomicAdd(&cur[bdl[i]], 1);
            ssrc[p] = bsrc[i];
        }
        __syncthreads();
    }
    if (blockIdx.x == 0 && tid == 0) rowptr[N] = E;
}

// --- dense transform: h[row,l] = sum_k lrelu?(x[row,k]) * W[k,l] ------------
template <int K, bool LRELU>
__global__ __launch_bounds__(256) void gemm_h(
    const float* __restrict__ x, const float* __restrict__ W,
    float* __restrict__ h, int n) {
    const int lane = threadIdx.x & 63;
    const int gw = blockIdx.x * (blockDim.x >> 6) + (threadIdx.x >> 6);
    const int nw = gridDim.x * (blockDim.x >> 6);

    float wreg[K];
#pragma unroll
    for (int k = 0; k < K; ++k) wreg[k] = W[k * 64 + lane];

    for (int row = gw; row < n; row += nw) {
        float xv0 = x[(size_t)row * K + lane];
        if (LRELU) xv0 = xv0 >= 0.f ? xv0 : 0.2f * xv0;
        float xv1 = 0.f;
        if (K == 128) {
            xv1 = x[(size_t)row * K + 64 + lane];
            if (LRELU) xv1 = xv1 >= 0.f ? xv1 : 0.2f * xv1;
        }
        float a0 = 0.f, a1 = 0.f, a2 = 0.f, a3 = 0.f;
#pragma unroll
        for (int k = 0; k < 64; k += 4) {
            a0 = fmaf(readlane_f(xv0, k + 0), wreg[k + 0], a0);
            a1 = fmaf(readlane_f(xv0, k + 1), wreg[k + 1], a1);
            a2 = fmaf(readlane_f(xv0, k + 2), wreg[k + 2], a2);
            a3 = fmaf(readlane_f(xv0, k + 3), wreg[k + 3], a3);
        }
        if (K == 128) {
#pragma unroll
            for (int k = 0; k < 64; k += 4) {
                a0 = fmaf(readlane_f(xv1, k + 0), wreg[64 + k + 0], a0);
                a1 = fmaf(readlane_f(xv1, k + 1), wreg[64 + k + 1], a1);
                a2 = fmaf(readlane_f(xv1, k + 2), wreg[64 + k + 2], a2);
                a3 = fmaf(readlane_f(xv1, k + 3), wreg[64 + k + 3], a3);
            }
        }
        h[(size_t)row * 64 + lane] = (a0 + a1) + (a2 + a3);
    }
}

// --- CSR aggregation: one wave per dst node, lane = feature -----------------
__global__ __launch_bounds__(256) void csr_agg64(
    const float* __restrict__ h, const int* __restrict__ rowptr,
    const int* __restrict__ ssrc, const float* __restrict__ dinv,
    const float* __restrict__ b, float* __restrict__ agg, int n) {
    const int lane = threadIdx.x & 63;
    int w = blockIdx.x * (blockDim.x >> 6) + (threadIdx.x >> 6);
    const int nw = gridDim.x * (blockDim.x >> 6);
    const float bl = b[lane];
    for (int d = w; d < n; d += nw) {
        const float di = dinv[d];
        float acc = fmaf(di * di, h[(size_t)d * 64 + lane], bl);
        int e = rowptr[d], end = rowptr[d + 1];
        for (; e + 4 <= end; e += 4) {
            int s0 = ssrc[e], s1 = ssrc[e + 1], s2 = ssrc[e + 2], s3 = ssrc[e + 3];
            float n0 = di * dinv[s0], n1 = di * dinv[s1];
            float n2 = di * dinv[s2], n3 = di * dinv[s3];
            float v0 = h[(size_t)s0 * 64 + lane], v1 = h[(size_t)s1 * 64 + lane];
            float v2 = h[(size_t)s2 * 64 + lane], v3 = h[(size_t)s3 * 64 + lane];
            acc = fmaf(v0, n0, acc);
            acc = fmaf(v1, n1, acc);
            acc = fmaf(v2, n2, acc);
            acc = fmaf(v3, n3, acc);
        }
        for (; e < end; ++e) {
            int s = ssrc[e];
            acc = fmaf(h[(size_t)s * 64 + lane], di * dinv[s], acc);
        }
        agg[(size_t)d * 64 + lane] = acc;
    }
}

// --- final layer: K=64 -> 4, lrelu on input ---------------------------------
__global__ __launch_bounds__(256) void gemm4_h(
    const float* __restrict__ x, const float* __restrict__ W,  // [64,4]
    float* __restrict__ h4, int n) {
    int i = blockIdx.x * blockDim.x + threadIdx.x;
    int stride = gridDim.x * blockDim.x;
    for (; i < n; i += stride) {
        const float4* xr = (const float4*)(x + (size_t)i * 64);
        float a0 = 0.f, a1 = 0.f, a2 = 0.f, a3 = 0.f;
#pragma unroll
        for (int k4 = 0; k4 < 16; ++k4) {
            float4 xv = xr[k4];
            float e0 = xv.x >= 0.f ? xv.x : 0.2f * xv.x;
            float e1 = xv.y >= 0.f ? xv.y : 0.2f * xv.y;
            float e2 = xv.z >= 0.f ? xv.z : 0.2f * xv.z;
            float e3 = xv.w >= 0.f ? xv.w : 0.2f * xv.w;
            int k = k4 * 4;
            a0 = fmaf(e0, W[(k + 0) * 4 + 0], a0); a1 = fmaf(e0, W[(k + 0) * 4 + 1], a1);
            a2 = fmaf(e0, W[(k + 0) * 4 + 2], a2); a3 = fmaf(e0, W[(k + 0) * 4 + 3], a3);
            a0 = fmaf(e1, W[(k + 1) * 4 + 0], a0); a1 = fmaf(e1, W[(k + 1) * 4 + 1], a1);
            a2 = fmaf(e1, W[(k + 1) * 4 + 2], a2); a3 = fmaf(e1, W[(k + 1) * 4 + 3], a3);
            a0 = fmaf(e2, W[(k + 2) * 4 + 0], a0); a1 = fmaf(e2, W[(k + 2) * 4 + 1], a1);
            a2 = fmaf(e2, W[(k + 2) * 4 + 2], a2); a3 = fmaf(e2, W[(k + 2) * 4 + 3], a3);
            a0 = fmaf(e3, W[(k + 3) * 4 + 0], a0); a1 = fmaf(e3, W[(k + 3) * 4 + 1], a1);
            a2 = fmaf(e3, W[(k + 3) * 4 + 2], a2); a3 = fmaf(e3, W[(k + 3) * 4 + 3], a3);
        }
        ((float4*)h4)[i] = make_float4(a0, a1, a2, a3);
    }
}

__global__ __launch_bounds__(256) void csr_agg4(
    const float* __restrict__ h4, const int* __restrict__ rowptr,
    const int* __restrict__ ssrc, const float* __restrict__ dinv,
    const float* __restrict__ b, float* __restrict__ out, int n) {
    int i = blockIdx.x * blockDim.x + threadIdx.x;
    int stride = gridDim.x * blockDim.x;
    float b0 = b[0], b1 = b[1], b2 = b[2], b3 = b[3];
    for (; i < n; i += stride) {
        float di = dinv[i];
        float d2 = di * di;
        float4 hv = ((const float4*)h4)[i];
        float a0 = fmaf(d2, hv.x, b0), a1 = fmaf(d2, hv.y, b1);
        float a2 = fmaf(d2, hv.z, b2), a3 = fmaf(d2, hv.w, b3);
        int e = rowptr[i], end = rowptr[i + 1];
        for (; e < end; ++e) {
            int s = ssrc[e];
            float nrm = di * dinv[s];
            float4 v = ((const float4*)h4)[s];
            a0 = fmaf(nrm, v.x, a0); a1 = fmaf(nrm, v.y, a1);
            a2 = fmaf(nrm, v.z, a2); a3 = fmaf(nrm, v.w, a3);
        }
        ((float4*)out)[i] = make_float4(a0, a1, a2, a3);
    }
}

static inline size_t al64(size_t x) { return (x + 63) & ~(size_t)63; }

extern "C" void kernel_launch(void* const* d_in, const int* in_sizes, int n_in,
                              void* d_out, int out_size, void* d_ws, size_t ws_size,
                              hipStream_t stream) {
    const float* x  = (const float*)d_in[0];
    const int* ei   = (const int*)d_in[1];
    const float* W0 = (const float*)d_in[2];
    const float* b0 = (const float*)d_in[3];
    const float* W1 = (const float*)d_in[4];
    const float* b1 = (const float*)d_in[5];
    const float* W2 = (const float*)d_in[6];
    const float* b2 = (const float*)d_in[7];
    const float* W3 = (const float*)d_in[8];
    const float* b3 = (const float*)d_in[9];
    const float* W4 = (const float*)d_in[10];
    const float* b4 = (const float*)d_in[11];
    const float* W5 = (const float*)d_in[12];
    const float* b5 = (const float*)d_in[13];

    const int N = in_sizes[0] / 128;
    const int E = in_sizes[1] / 2;
    const int* src  = ei;       // edge_index[0] = message sources
    const int* dstp = ei + E;   // edge_index[1] = aggregation targets
    const int NB = (N + 127) >> 7;   // dst buckets of 128 ids (NB <= 1024)

    float* ws = (float*)d_ws;
    size_t off = 0;
    int*   rowptr = (int*)(ws + off);   off += al64((size_t)N + 1);
    float* dinv   = ws + off;           off += al64((size_t)N);
    int*   ssrc   = (int*)(ws + off);   off += al64((size_t)E);
    float* bufA   = ws + off;           off += (size_t)64 * N;
    float* bufB   = ws + off;

    // build temps alias into bufA (released before layer 0 writes bufA)
    int* ghist = (int*)bufA;                       // [1024]
    int* bbase = ghist + 1024;                     // [NB+1]
    int* bcur  = bbase + 1088;                     // [NB]
    int* bsrc  = (int*)(bufA + 4096);              // [E]
    unsigned char* bdl = (unsigned char*)(bsrc + E);  // [E]

    // ---- graph build (bucketed counting sort) ----
    hipMemsetAsync(ghist, 0, 1024 * sizeof(int), stream);
    bucket_hist<<<391, 256, 0, stream>>>(dstp, ghist, E, NB);
    bucket_scan<<<1, 1024, 0, stream>>>(ghist, bbase, bcur, NB, E);
    bucket_scatter<<<391, 256, 0, stream>>>(src, dstp, bcur, bsrc, bdl, E, NB);
    bucket_finalize<<<NB, 256, 0, stream>>>(bbase, bsrc, bdl, rowptr, ssrc, dinv, N, NB, E);

    // ---- layer 0: x[N,128] ----
    gemm_h<128, false><<<2048, 256, 0, stream>>>(x, W0, bufA, N);
    csr_agg64<<<2048, 256, 0, stream>>>(bufA, rowptr, ssrc, dinv, b0, bufB, N);

    // ---- layers 1-4 ----
    const float* Ws[4] = {W1, W2, W3, W4};
    const float* bs[4] = {b1, b2, b3, b4};
    for (int l = 0; l < 4; ++l) {
        gemm_h<64, true><<<2048, 256, 0, stream>>>(bufB, Ws[l], bufA, N);
        csr_agg64<<<2048, 256, 0, stream>>>(bufA, rowptr, ssrc, dinv, bs[l], bufB, N);
    }

    // ---- layer 5: 64 -> 4 ----
    gemm4_h<<<1024, 256, 0, stream>>>(bufB, W5, bufA, N);
    csr_agg4<<<2048, 256, 0, stream>>>(bufA, rowptr, ssrc, dinv, b5, (float*)d_out, N);
}